// Round 1
// baseline (2985.482 us; speedup 1.0000x reference)
//
#include <hip/hip_runtime.h>
#include <stdint.h>

// BayesLSTM: 2-layer LSTM with reparameterized (mu + exp(0.5*lv)*eps) weights
// resampled EVERY timestep from JAX threefry streams (partitionable mode).
//
// Design R0 (correctness-first):
//   prologue + 129 step launches. Launch t: layer0 step t (blocks 0..127),
//   layer1 step t-1 (blocks 128..255), each also generating the NEXT step's
//   sampled weights into a double-buffered ws slot. Stream ordering between
//   launches provides all synchronization (no cooperative launch).
//
// ws layout (floats):
//   [2 x SZ0] layer-0 weight slots  (K-major: [k][1024] then bih, bhh)
//   [2 x SZ1] layer-1 weight slots
//   [2 x B*H] hs0 ring (layer0 -> layer1 handoff)
//   [2 x B*H] h0 double buffer, [2 x B*H] h1 double buffer
//   [B*H] c0, [B*H] c1

typedef unsigned int u32;

#define Bn 64
#define Tn 128
#define INn 64
#define Hn 256
#define Gn 1024

#define SZ0 ((INn + Hn) * Gn + 2 * Gn)   // 329728
#define SZ1 ((Hn + Hn) * Gn + 2 * Gn)    // 526336
#define OFF_WL1  (2 * SZ0)
#define OFF_RING (2 * SZ0 + 2 * SZ1)
#define OFF_H0   (OFF_RING + 2 * Bn * Hn)
#define OFF_H1   (OFF_H0 + 2 * Bn * Hn)
#define OFF_C0   (OFF_H1 + 2 * Bn * Hn)
#define OFF_C1   (OFF_C0 + Bn * Hn)
#define WS_FLOATS (OFF_C1 + Bn * Hn)     // 1843200 floats = 7.03 MiB
#define STATE_FLOATS (WS_FLOATS - OFF_RING)
#define OUT_HN (Bn * Tn * Hn)

struct KP { u32 a, b; };

// Threefry-2x32, 20 rounds — matches jax/_src/prng.py exactly.
__device__ __forceinline__ KP tf(u32 k0, u32 k1, u32 x0, u32 x1) {
  u32 ks2 = k0 ^ k1 ^ 0x1BD11BDAu;
  x0 += k0; x1 += k1;
#define TFR(r) { x0 += x1; x1 = (x1 << (r)) | (x1 >> (32 - (r))); x1 ^= x0; }
  TFR(13) TFR(15) TFR(26) TFR(6)
  x0 += k1;  x1 += ks2 + 1u;
  TFR(17) TFR(29) TFR(16) TFR(24)
  x0 += ks2; x1 += k0 + 2u;
  TFR(13) TFR(15) TFR(26) TFR(6)
  x0 += k0;  x1 += k1 + 3u;
  TFR(17) TFR(29) TFR(16) TFR(24)
  x0 += k1;  x1 += ks2 + 4u;
  TFR(13) TFR(15) TFR(26) TFR(6)
  x0 += ks2; x1 += k0 + 5u;
#undef TFR
  KP o; o.a = x0; o.b = x1; return o;
}

// bits -> N(0,1), matching jax.random.normal f32:
//   u = max(lo, ((bits>>9)|0x3f800000 as float - 1) * (1-lo) ... ) with
//   lo = nextafter(-1,0); (hi-lo) rounds to 2.0f in f32.
//   normal = sqrt(2)_f32 * erfinv(u), erfinv = XLA/Giles polynomial.
__device__ __forceinline__ float n01(u32 bits) {
  float f = __uint_as_float((bits >> 9) | 0x3f800000u) - 1.0f;
  float u = fmaxf(-0.99999994f, f * 2.0f - 0.99999994f);
  float w = -log1pf(-u * u);
  float p;
  if (w < 5.0f) {
    float z = w - 2.5f;
    p = 2.81022636e-08f;
    p = 3.43273939e-07f  + p * z;
    p = -3.5233877e-06f  + p * z;
    p = -4.39150654e-06f + p * z;
    p = 0.00021858087f   + p * z;
    p = -0.00125372503f  + p * z;
    p = -0.00417768164f  + p * z;
    p = 0.246640727f     + p * z;
    p = 1.50140941f      + p * z;
  } else {
    float z = sqrtf(w) - 3.0f;
    p = -0.000200214257f;
    p = 0.000100950558f  + p * z;
    p = 0.00134934322f   + p * z;
    p = -0.00367342844f  + p * z;
    p = 0.00573950773f   + p * z;
    p = -0.0076224613f   + p * z;
    p = 0.00943887047f   + p * z;
    p = 1.00167406f      + p * z;
    p = 2.83297682f      + p * z;
  }
  return 1.41421356237f * (p * u);
}

// Generate one (layer, step) weight slot. Storage: unified K-major weight
// block W_T[k][g] for k in [0, Kin+H) (wih rows first, then whh rows),
// followed by bih[1024], bhh[1024]. Noise index i is the JAX row-major flat
// index of the (G, K) parameter array (partitionable: bits = y0^y1 of
// enc(array_key, (0, i))).
__device__ void produce_weights(int layer, int tt, float* __restrict__ slot,
    const float* __restrict__ wihmu, const float* __restrict__ wihlv,
    const float* __restrict__ whhmu, const float* __restrict__ whhlv,
    const float* __restrict__ bihmu, const float* __restrict__ bihlv,
    const float* __restrict__ bhhmu, const float* __restrict__ bhhlv,
    int Kin, int worker, int nworkers)
{
  KP lk  = tf(0u, 42u, 0u, (u32)layer);     // fold_in(key(42), layer)
  KP kt  = tf(lk.a, lk.b, 0u, (u32)tt);     // split(layer_key, T)[tt]
  KP kw  = tf(kt.a, kt.b, 0u, 0u);          // k1 -> wih
  KP ku  = tf(kt.a, kt.b, 0u, 1u);          // k2 -> whh
  KP kbi = tf(kt.a, kt.b, 0u, 2u);          // k3 -> bih
  KP kbh = tf(kt.a, kt.b, 0u, 3u);          // k4 -> bhh
  const int nwu = (Kin + Hn) * Gn;
  const int n = nwu + 2 * Gn;
  for (int idx = worker; idx < n; idx += nworkers) {
    u32 ka, kb; int i; const float* mu; const float* lv;
    if (idx < nwu) {
      int kk = idx >> 10, g = idx & (Gn - 1);
      if (kk < Kin) { i = g * Kin + kk;        ka = kw.a;  kb = kw.b;  mu = wihmu; lv = wihlv; }
      else          { i = g * Hn + (kk - Kin); ka = ku.a;  kb = ku.b;  mu = whhmu; lv = whhlv; }
    } else if (idx < nwu + Gn) {
      i = idx - nwu;      ka = kbi.a; kb = kbi.b; mu = bihmu; lv = bihlv;
    } else {
      i = idx - nwu - Gn; ka = kbh.a; kb = kbh.b; mu = bhhmu; lv = bhhlv;
    }
    KP r2 = tf(ka, kb, 0u, (u32)i);
    slot[idx] = mu[i] + expf(0.5f * lv[i]) * n01(r2.a ^ r2.b);
  }
}

__global__ __launch_bounds__(256) void bayes_lstm_step(
    const float* __restrict__ x,
    const float* __restrict__ wihmu0, const float* __restrict__ wihlv0,
    const float* __restrict__ whhmu0, const float* __restrict__ whhlv0,
    const float* __restrict__ bihmu0, const float* __restrict__ bihlv0,
    const float* __restrict__ bhhmu0, const float* __restrict__ bhhlv0,
    const float* __restrict__ wihmu1, const float* __restrict__ wihlv1,
    const float* __restrict__ whhmu1, const float* __restrict__ whhlv1,
    const float* __restrict__ bihmu1, const float* __restrict__ bihlv1,
    const float* __restrict__ bhhmu1, const float* __restrict__ bhhlv1,
    float* __restrict__ ws, float* __restrict__ out, int t)
{
  const int tid = threadIdx.x;
  const int bid = blockIdx.x;
  const int layer = bid >> 7;     // 0: blocks 0..127, 1: blocks 128..255
  const int lb = bid & 127;

  __shared__ float inb[8][512];        // 8 batch rows x (Kin+H) inputs
  __shared__ float wtile[64][68];      // 64 k x 64 cols (+4 pad)
  __shared__ float gpart[16][8][64];   // k-split partial gates

  const int ts  = layer ? (t - 1) : t;            // step this layer processes
  const int Kin = layer ? Hn : INn;
  const int Ktot = Kin + Hn;
  float* slot = layer ? (ws + OFF_WL1 + (ts & 1) * SZ1) : (ws + (ts & 1) * SZ0);
  float* ring = ws + OFF_RING;

  const bool doc = layer ? (t >= 1) : (t < Tn);

  if (doc) {
    const int ct = lb & 15, bc = lb >> 4;
    const int j0 = ct * 16, b0 = bc * 8;
    const float* hprev = layer ? (ws + OFF_H1 + (ts & 1) * (Bn * Hn))
                               : (ws + OFF_H0 + (ts & 1) * (Bn * Hn));
    // stage the 8 input rows: [0,Kin) = x_t (or hs0), [Kin,Kin+H) = h_prev
    for (int ii = tid; ii < 8 * Ktot; ii += 256) {
      int r = ii / Ktot, p = ii - r * Ktot;
      float v;
      if (p < Kin)
        v = layer ? ring[(ts & 1) * (Bn * Hn) + (b0 + r) * Hn + p]
                  : x[(b0 + r) * (Tn * INn) + ts * INn + p];
      else
        v = hprev[(b0 + r) * Hn + (p - Kin)];
      inb[r][p] = v;
    }

    const int cg = tid & 15, kq = tid >> 4;   // 16 col-groups x 16 k-slices
    const int c4 = cg * 4;
    float acc[8][4];
    #pragma unroll
    for (int r = 0; r < 8; ++r) { acc[r][0] = acc[r][1] = acc[r][2] = acc[r][3] = 0.f; }

    __syncthreads();
    const int nch = Ktot >> 6;
    for (int ch = 0; ch < nch; ++ch) {
      // stage 64-k chunk of the 64 columns this block owns
      {
        int c = tid & 63, kq4 = tid >> 6;                      // 4 k-quarters
        int colg = ((c >> 4) << 8) + j0 + (c & 15);            // slice*256+j0+jj
        for (int kk = kq4 * 16; kk < kq4 * 16 + 16; ++kk)
          wtile[kk][c] = slot[(ch * 64 + kk) * Gn + colg];
      }
      __syncthreads();
      {
        const int kb = kq * 4;
        const int ka = ch * 64 + kb;
        float4 w0 = *(const float4*)&wtile[kb + 0][c4];
        float4 w1 = *(const float4*)&wtile[kb + 1][c4];
        float4 w2 = *(const float4*)&wtile[kb + 2][c4];
        float4 w3 = *(const float4*)&wtile[kb + 3][c4];
        #pragma unroll
        for (int r = 0; r < 8; ++r) {
          float4 in4 = *(const float4*)&inb[r][ka];
          acc[r][0] += in4.x * w0.x + in4.y * w1.x + in4.z * w2.x + in4.w * w3.x;
          acc[r][1] += in4.x * w0.y + in4.y * w1.y + in4.z * w2.y + in4.w * w3.y;
          acc[r][2] += in4.x * w0.z + in4.y * w1.z + in4.z * w2.z + in4.w * w3.z;
          acc[r][3] += in4.x * w0.w + in4.y * w1.w + in4.z * w2.w + in4.w * w3.w;
        }
      }
      __syncthreads();
    }
    #pragma unroll
    for (int r = 0; r < 8; ++r) {
      float4 v; v.x = acc[r][0]; v.y = acc[r][1]; v.z = acc[r][2]; v.w = acc[r][3];
      *(float4*)&gpart[kq][r][c4] = v;
    }
    __syncthreads();

    if (tid < 128) {
      const int bl = tid >> 4, jj = tid & 15;
      const int b = b0 + bl, j = j0 + jj;
      const float* bih = slot + Ktot * Gn;
      const float* bhh = bih + Gn;
      float g4[4];
      #pragma unroll
      for (int s = 0; s < 4; ++s) {
        const int cl = s * 16 + jj;
        float sum = 0.f;
        #pragma unroll
        for (int q = 0; q < 16; ++q) sum += gpart[q][bl][cl];
        g4[s] = sum + bih[s * Hn + j] + bhh[s * Hn + j];
      }
      float* cst = layer ? (ws + OFF_C1) : (ws + OFF_C0);
      float cp = cst[b * Hn + j];
      float si = 1.0f / (1.0f + expf(-g4[0]));
      float sf = 1.0f / (1.0f + expf(-g4[1]));
      float so = 1.0f / (1.0f + expf(-g4[3]));
      float cn = sf * cp + si * tanhf(g4[2]);
      float hn = so * tanhf(cn);
      cst[b * Hn + j] = cn;
      float* hnx = layer ? (ws + OFF_H1 + ((ts + 1) & 1) * (Bn * Hn))
                         : (ws + OFF_H0 + ((ts + 1) & 1) * (Bn * Hn));
      hnx[b * Hn + j] = hn;
      if (layer == 0) {
        ring[(ts & 1) * (Bn * Hn) + b * Hn + j] = hn;
        if (ts == Tn - 1) {
          out[OUT_HN + b * Hn + j] = hn;                 // h_n[0]
          out[OUT_HN + 2 * Bn * Hn + b * Hn + j] = cn;   // c_n[0]
        }
      } else {
        out[b * (Tn * Hn) + ts * Hn + j] = hn;           // output[b][t][j]
        if (ts == Tn - 1) {
          out[OUT_HN + Bn * Hn + b * Hn + j] = hn;       // h_n[1]
          out[OUT_HN + 3 * Bn * Hn + b * Hn + j] = cn;   // c_n[1]
        }
      }
    }
  }

  // produce NEXT step's weights (off the critical path; consumed next launch)
  const int tt = layer ? t : (t + 1);
  const bool dop = layer ? (t < Tn) : (t + 1 < Tn);
  if (dop) {
    float* pslot = layer ? (ws + OFF_WL1 + (tt & 1) * SZ1) : (ws + (tt & 1) * SZ0);
    if (layer == 0)
      produce_weights(0, tt, pslot, wihmu0, wihlv0, whhmu0, whhlv0,
                      bihmu0, bihlv0, bhhmu0, bhhlv0, INn, lb * 256 + tid, 128 * 256);
    else
      produce_weights(1, tt, pslot, wihmu1, wihlv1, whhmu1, whhlv1,
                      bihmu1, bihlv1, bhhmu1, bhhlv1, Hn, lb * 256 + tid, 128 * 256);
  }
}

__global__ __launch_bounds__(256) void bayes_lstm_prologue(
    const float* __restrict__ wihmu0, const float* __restrict__ wihlv0,
    const float* __restrict__ whhmu0, const float* __restrict__ whhlv0,
    const float* __restrict__ bihmu0, const float* __restrict__ bihlv0,
    const float* __restrict__ bhhmu0, const float* __restrict__ bhhlv0,
    float* __restrict__ ws)
{
  const int w = blockIdx.x * 256 + threadIdx.x;
  for (int i = w; i < STATE_FLOATS; i += 256 * 256)
    ws[OFF_RING + i] = 0.0f;                          // zero h/c/ring state
  produce_weights(0, 0, ws, wihmu0, wihlv0, whhmu0, whhlv0,
                  bihmu0, bihlv0, bhhmu0, bhhlv0, INn, w, 256 * 256);
}

extern "C" void kernel_launch(void* const* d_in, const int* in_sizes, int n_in,
                              void* d_out, int out_size, void* d_ws, size_t ws_size,
                              hipStream_t stream) {
  (void)in_sizes; (void)n_in; (void)out_size;
  if (ws_size < (size_t)WS_FLOATS * sizeof(float)) return;  // need 7.03 MiB

  const float* x      = (const float*)d_in[0];
  const float* wihmu0 = (const float*)d_in[1];
  const float* wihlv0 = (const float*)d_in[2];
  const float* whhmu0 = (const float*)d_in[3];
  const float* whhlv0 = (const float*)d_in[4];
  const float* bihmu0 = (const float*)d_in[5];
  const float* bihlv0 = (const float*)d_in[6];
  const float* bhhmu0 = (const float*)d_in[7];
  const float* bhhlv0 = (const float*)d_in[8];
  const float* wihmu1 = (const float*)d_in[9];
  const float* wihlv1 = (const float*)d_in[10];
  const float* whhmu1 = (const float*)d_in[11];
  const float* whhlv1 = (const float*)d_in[12];
  const float* bihmu1 = (const float*)d_in[13];
  const float* bihlv1 = (const float*)d_in[14];
  const float* bhhmu1 = (const float*)d_in[15];
  const float* bhhlv1 = (const float*)d_in[16];
  float* ws  = (float*)d_ws;
  float* out = (float*)d_out;

  bayes_lstm_prologue<<<dim3(256), dim3(256), 0, stream>>>(
      wihmu0, wihlv0, whhmu0, whhlv0, bihmu0, bihlv0, bhhmu0, bhhlv0, ws);

  for (int t = 0; t <= Tn; ++t) {
    bayes_lstm_step<<<dim3(256), dim3(256), 0, stream>>>(
        x,
        wihmu0, wihlv0, whhmu0, whhlv0, bihmu0, bihlv0, bhhmu0, bhhlv0,
        wihmu1, wihlv1, whhmu1, whhlv1, bihmu1, bihlv1, bhhmu1, bhhlv1,
        ws, out, t);
  }
}